// Round 7
// baseline (141.653 us; speedup 1.0000x reference)
//
#include <hip/hip_runtime.h>
#include <hip/hip_bf16.h>

typedef short bf16x8 __attribute__((ext_vector_type(8)));
typedef short short8 __attribute__((ext_vector_type(8)));
typedef float f32x4  __attribute__((ext_vector_type(4)));

#define D     128
#define CH    16          // edges per wave-chunk
#define WAVES 8           // waves per block
#define BLK   (WAVES*64)  // 512 threads
#define NB    2048        // sort buckets
#define SBLK  512         // sort blocks
#define STHR  256         // sort threads/block

// f32 -> bf16 round-to-nearest-even (finite inputs)
__device__ __forceinline__ short f2bf(float f) {
    unsigned u = __float_as_uint(f);
    u = (u + 0x7fffu + ((u >> 16) & 1u)) >> 16;
    return (short)u;
}
__device__ __forceinline__ float bf2f(short s) {
    return __uint_as_float(((unsigned)(unsigned short)s) << 16);
}

// LDS byte offset for [row][128 bf16], XOR-swizzled (16B-granular, G4).
__device__ __forceinline__ int swz(int row, int intra) {
    return (row << 8) + (intra ^ ((row & 7) << 4));
}

// ---- prep: swizzled W1^T bf16 image (32 KB) ----
__global__ void prep_w1(const float* __restrict__ W1, short* __restrict__ ws) {
    const int idx = blockIdx.x * 256 + threadIdx.x;   // 64 x 256 = 16384
    const int k = idx >> 7, c = idx & 127;            // W1 is [k][c]
    ws[((c << 8) + ((2 * k) ^ ((c & 7) << 4))) >> 1] = f2bf(W1[idx]);
}

// ---- prep: f32 tables -> bf16 tables (halves gather bytes) ----
__global__ void conv_both(const float* __restrict__ l, const float* __restrict__ r,
                          short* __restrict__ lb, short* __restrict__ rb,
                          int n8l, int n8r) {
    int i = blockIdx.x * blockDim.x + threadIdx.x;
    const int st = gridDim.x * blockDim.x;
    for (; i < n8l + n8r; i += st) {
        const float* s; short* d; int j;
        if (i < n8l) { s = l; d = lb; j = i; }
        else         { s = r; d = rb; j = i - n8l; }
        const f32x4 a = ((const f32x4*)s)[2 * j];
        const f32x4 b = ((const f32x4*)s)[2 * j + 1];
        short8 o;
        o[0]=f2bf(a[0]); o[1]=f2bf(a[1]); o[2]=f2bf(a[2]); o[3]=f2bf(a[3]);
        o[4]=f2bf(b[0]); o[5]=f2bf(b[1]); o[6]=f2bf(b[2]); o[7]=f2bf(b[3]);
        ((short8*)d)[i < n8l ? j : j] = o; // (j already adjusted)
    }
}

// ---- sort pass 1: per-block LDS histogram + global reservation ----
__global__ __launch_bounds__(STHR)
void edge_histo(const int* __restrict__ pairs, int E, float scale,
                int* __restrict__ counts, int* __restrict__ bases) {
    __shared__ int h[NB];
    for (int b = threadIdx.x; b < NB; b += STHR) h[b] = 0;
    __syncthreads();
    const int epb = (E + SBLK - 1) / SBLK;
    const int lo = blockIdx.x * epb, hi = min(lo + epb, E);
    for (int e = lo + threadIdx.x; e < hi; e += STHR) {
        const int bkt = min(NB - 1, (int)((float)pairs[e] * scale));
        atomicAdd(&h[bkt], 1);
    }
    __syncthreads();
    for (int b = threadIdx.x; b < NB; b += STHR) {
        const int v = h[b];
        if (v) bases[blockIdx.x * NB + b] = atomicAdd(&counts[b], v);
    }
}

// ---- sort pass 2: exclusive scan of bucket counts (in place), 1 block ----
__global__ __launch_bounds__(1024)
void bucket_scan(int* __restrict__ counts) {
    __shared__ int a[1024], b[1024];
    const int t = threadIdx.x;
    const int c0 = counts[2 * t], c1 = counts[2 * t + 1];
    a[t] = c0 + c1;
    __syncthreads();
    int* src = a; int* dst = b;
    for (int off = 1; off < 1024; off <<= 1) {
        int v = src[t];
        if (t >= off) v += src[t - off];
        __syncthreads();            // protect src reads before overwrite
        dst[t] = v;
        __syncthreads();
        int* tmp = src; src = dst; dst = tmp;
    }
    const int excl = src[t] - (c0 + c1);   // exclusive pair-scan
    counts[2 * t]     = excl;
    counts[2 * t + 1] = excl + c0;
}

// ---- sort pass 3: scatter (i0,i1,eid) records into bucket order ----
__global__ __launch_bounds__(STHR)
void edge_scatter(const int* __restrict__ pairs, int E, float scale,
                  const int* __restrict__ starts, const int* __restrict__ bases,
                  int4* __restrict__ recs) {
    __shared__ int rk[NB];
    for (int b = threadIdx.x; b < NB; b += STHR) rk[b] = 0;
    __syncthreads();
    const int epb = (E + SBLK - 1) / SBLK;
    const int lo = blockIdx.x * epb, hi = min(lo + epb, E);
    for (int e = lo + threadIdx.x; e < hi; e += STHR) {
        const int i0 = pairs[e], i1 = pairs[E + e];
        const int bkt = min(NB - 1, (int)((float)i0 * scale));
        const int r = atomicAdd(&rk[bkt], 1);
        const int slot = starts[bkt] + bases[blockIdx.x * NB + bkt] + r;
        recs[slot] = make_int4(i0, i1, e, 0);
    }
}

// MODE 0: f32 unsorted (fallback). MODE 1: bf16 unsorted. MODE 2: bf16 sorted.
template <int MODE>
__global__ __launch_bounds__(BLK, 4)
void edge_decoder_kernel(const float* __restrict__ left,
                         const float* __restrict__ right,
                         const short* __restrict__ leftb,
                         const short* __restrict__ rightb,
                         const int* __restrict__ pairs,
                         const int4* __restrict__ recs,
                         const short* __restrict__ w1ws,
                         const float* __restrict__ b1,
                         const float* __restrict__ W2,
                         const float* __restrict__ b2,
                         float* __restrict__ out, int E)
{
    __shared__ char smem[65536];
    char* const w1t = smem;                                     // 32 KB
    char* const xls = smem + 32768 + (threadIdx.x >> 6) * 4096; // wave-private

    const int tid  = threadIdx.x;
    const int lane = tid & 63;
    const int wid  = tid >> 6;
    const int lg   = lane >> 4;
    const int lm   = lane & 15;
    const int half = lane >> 5;
    const int l32  = lane & 31;

    for (int j = tid; j < 2048; j += BLK)          // W1^T: linear copy
        *(f32x4*)(w1t + j * 16) = ((const f32x4*)w1ws)[j];

    float b1v[8], w2v[8];
    #pragma unroll
    for (int ct = 0; ct < 8; ++ct) {
        b1v[ct] = b1[ct * 16 + lm];
        w2v[ct] = W2[ct * 16 + lm];
    }
    const float b2s = b2[0];
    __syncthreads();

    const int chunks = (E + CH - 1) / CH;

    // chunk range: MODE 2 = contiguous per block (left-locality);
    // MODE 0/1 = grid-stride as before.
    int c, hiC, stepC;
    if (MODE == 2) {
        const int cpb = (chunks + gridDim.x - 1) / gridDim.x;
        c = blockIdx.x * cpb + wid;
        hiC = min(blockIdx.x * cpb + cpb, chunks);
        stepC = WAVES;
    } else {
        c = blockIdx.x * WAVES + wid;
        hiC = chunks;
        stepC = gridDim.x * WAVES;
    }
    if (c >= hiC) return;

    // per-chunk edge info loaders (lanes use lm; all lanes hold copies)
    auto ld_sorted = [&](int cc, int& i0v, int& i1v, int& eidv) {
        const int slot = cc * CH + lm;
        if (slot < E) {
            const int4 r = recs[slot];
            i0v = r.x; i1v = r.y; eidv = r.z;
        } else { i0v = 0; i1v = 0; eidv = -1; }
    };
    auto ld_plain = [&](int cc, int& i0v, int& i1v, int& eidv) {
        int e0 = cc * CH + lm;
        eidv = (e0 < E) ? e0 : -1;
        if (e0 >= E) e0 = E - 1;
        i0v = pairs[e0]; i1v = pairs[E + e0];
    };

    int i0v, i1v, eidv;
    if (MODE == 2) ld_sorted(c, i0v, i1v, eidv); else ld_plain(c, i0v, i1v, eidv);

    while (true) {
        const int cn = c + stepC;
        const bool has = cn < hiC;
        int i0n = 0, i1n = 0, eidn = -1;
        if (has) {                       // prefetch next chunk's records
            if (MODE == 2) ld_sorted(cn, i0n, i1n, eidn);
            else           ld_plain(cn, i0n, i1n, eidn);
        }

        if (MODE >= 1) {
            // bf16 gather: 16B/lane, 16 lanes/row -> 4 rows/instr, burst
            const int q  = lane >> 4;
            const int lq = lane & 15;
            short8 lv[4], rv[4];
            #pragma unroll
            for (int j = 0; j < 4; ++j) {
                const int iL = __shfl(i0v, 4 * j + q);
                lv[j] = *(const short8*)(leftb + iL * D + lq * 8);
            }
            #pragma unroll
            for (int j = 0; j < 4; ++j) {
                const int iR = __shfl(i1v, 4 * j + q);
                rv[j] = *(const short8*)(rightb + iR * D + lq * 8);
            }
            #pragma unroll
            for (int j = 0; j < 4; ++j) {
                short8 xb;
                #pragma unroll
                for (int e = 0; e < 8; ++e)
                    xb[e] = f2bf(bf2f(lv[j][e]) * bf2f(rv[j][e]));
                *(short8*)(xls + swz(4 * j + q, lq * 16)) = xb;
            }
        } else {
            // f32 gather fallback: whole-row float4 reads, burst
            float4 lv[8], rv[8];
            #pragma unroll
            for (int j = 0; j < 8; ++j) {
                const int eoff = 2 * j + half;
                const int iL = __shfl(i0v, eoff);
                const int iR = __shfl(i1v, eoff);
                lv[j] = *(const float4*)(left  + iL * D + l32 * 4);
                rv[j] = *(const float4*)(right + iR * D + l32 * 4);
            }
            #pragma unroll
            for (int j = 0; j < 8; ++j) {
                const int eoff = 2 * j + half;
                short4 xb;
                xb.x = f2bf(lv[j].x * rv[j].x);
                xb.y = f2bf(lv[j].y * rv[j].y);
                xb.z = f2bf(lv[j].z * rv[j].z);
                xb.w = f2bf(lv[j].w * rv[j].w);
                *(short4*)(xls + swz(eoff, l32 * 8)) = xb;
            }
        }

        // MFMA: A and B share the same k-mapping (K-perm invariant)
        bf16x8 afr[4];
        #pragma unroll
        for (int kt = 0; kt < 4; ++kt)
            afr[kt] = *(const bf16x8*)(xls + swz(lm, kt * 64 + lg * 16));

        f32x4 acc[8];
        #pragma unroll
        for (int ct = 0; ct < 8; ++ct) acc[ct] = (f32x4){0.f, 0.f, 0.f, 0.f};

        #pragma unroll
        for (int kt = 0; kt < 4; ++kt)
            #pragma unroll
            for (int ct = 0; ct < 8; ++ct) {
                const bf16x8 bfr = *(const bf16x8*)(
                    w1t + swz(ct * 16 + lm, kt * 64 + lg * 16));
                acc[ct] = __builtin_amdgcn_mfma_f32_16x16x32_bf16(
                    afr[kt], bfr, acc[ct], 0, 0, 0);
            }

        // bias + ReLU + dot(W2) + 16-lane reduce + sigmoid
        // C-frag layout (HW-measured): col = lane&15, row = (lane>>4)*4+reg.
        float p0 = 0.f, p1 = 0.f, p2 = 0.f, p3 = 0.f;
        #pragma unroll
        for (int ct = 0; ct < 8; ++ct) {
            float h0 = fmaxf(acc[ct][0] + b1v[ct], 0.f);
            float h1 = fmaxf(acc[ct][1] + b1v[ct], 0.f);
            float h2 = fmaxf(acc[ct][2] + b1v[ct], 0.f);
            float h3 = fmaxf(acc[ct][3] + b1v[ct], 0.f);
            p0 = fmaf(h0, w2v[ct], p0);
            p1 = fmaf(h1, w2v[ct], p1);
            p2 = fmaf(h2, w2v[ct], p2);
            p3 = fmaf(h3, w2v[ct], p3);
        }
        #pragma unroll
        for (int s = 1; s < 16; s <<= 1) {
            p0 += __shfl_xor(p0, s);
            p1 += __shfl_xor(p1, s);
            p2 += __shfl_xor(p2, s);
            p3 += __shfl_xor(p3, s);
        }
        const int myeid = __shfl(eidv, (lg * 4 + lm) & 15); // slot's orig edge
        if (lm < 4 && myeid >= 0) {
            const float pv = (lm & 2) ? ((lm & 1) ? p3 : p2)
                                      : ((lm & 1) ? p1 : p0);
            out[myeid] = 1.f / (1.f + __expf(-(pv + b2s)));
        }

        if (!has) break;
        c = cn; i0v = i0n; i1v = i1n; eidv = eidn;
    }
}

extern "C" void kernel_launch(void* const* d_in, const int* in_sizes, int n_in,
                              void* d_out, int out_size, void* d_ws, size_t ws_size,
                              hipStream_t stream) {
    const float* left  = (const float*)d_in[0];
    const float* right = (const float*)d_in[1];
    const int*   pairs = (const int*)d_in[2];
    const float* W1    = (const float*)d_in[3];
    const float* b1    = (const float*)d_in[4];
    const float* W2    = (const float*)d_in[5];
    const float* b2    = (const float*)d_in[6];
    float* out = (float*)d_out;

    const int E  = in_sizes[2] / 2;                // pairs is [2][E]
    const int nn = in_sizes[0] / D;                // node count
    const int chunks = (E + CH - 1) / CH;
    const float scale = (float)NB / (float)nn;

    char* const ws = (char*)d_ws;
    const size_t offL   = 32768;
    const size_t szL    = (size_t)in_sizes[0] * 2;
    const size_t offR   = offL + szL;
    const size_t szR    = (size_t)in_sizes[1] * 2;
    const size_t offCnt = offR + szR;
    const size_t offBas = offCnt + (size_t)NB * 4;
    const size_t offRec = offBas + (size_t)SBLK * NB * 4;
    const size_t needSort = offRec + (size_t)chunks * CH * 16;
    const size_t needBf   = offCnt;

    short* const w1img  = (short*)ws;
    short* const leftb  = (short*)(ws + offL);
    short* const rightb = (short*)(ws + offR);
    int*   const counts = (int*)(ws + offCnt);
    int*   const bases  = (int*)(ws + offBas);
    int4*  const recs   = (int4*)(ws + offRec);

    prep_w1<<<64, 256, 0, stream>>>(W1, w1img);

    if (ws_size >= needSort) {
        conv_both<<<2048, 256, 0, stream>>>(left, right, leftb, rightb,
                                            in_sizes[0] / 8, in_sizes[1] / 8);
        hipMemsetAsync(counts, 0, NB * 4, stream);
        edge_histo<<<SBLK, STHR, 0, stream>>>(pairs, E, scale, counts, bases);
        bucket_scan<<<1, 1024, 0, stream>>>(counts);
        edge_scatter<<<SBLK, STHR, 0, stream>>>(pairs, E, scale, counts, bases, recs);
        int blocks = 512;
        edge_decoder_kernel<2><<<blocks, BLK, 0, stream>>>(
            left, right, leftb, rightb, pairs, recs, w1img, b1, W2, b2, out, E);
    } else if (ws_size >= needBf) {
        conv_both<<<2048, 256, 0, stream>>>(left, right, leftb, rightb,
                                            in_sizes[0] / 8, in_sizes[1] / 8);
        int blocks = 512;
        const int need = (chunks + WAVES - 1) / WAVES;
        if (need < blocks) blocks = need;
        edge_decoder_kernel<1><<<blocks, BLK, 0, stream>>>(
            left, right, leftb, rightb, pairs, recs, w1img, b1, W2, b2, out, E);
    } else {
        int blocks = 512;
        const int need = (chunks + WAVES - 1) / WAVES;
        if (need < blocks) blocks = need;
        edge_decoder_kernel<0><<<blocks, BLK, 0, stream>>>(
            left, right, leftb, rightb, pairs, recs, w1img, b1, W2, b2, out, E);
    }
}